// Round 19
// baseline (173.475 us; speedup 1.0000x reference)
//
#include <hip/hip_runtime.h>
#include <hip/hip_fp16.h>

#define Q_TOT 1024
#define T_TOT 256
#define NPTS  100
#define KD    300
#define EPSV  1e-6f

#define KSTEPS 10            // 10 * 32 = 320 >= 300 (zero-padded K)
#define EXTOFF 40            // front zero-pad for padded rows
#define EXTLEN 672           // f16 units per rotated copy

typedef _Float16 f16;
typedef _Float16 f16x8 __attribute__((ext_vector_type(8)));
typedef float    f32x4 __attribute__((ext_vector_type(4)));
#define MFMA16 __builtin_amdgcn_mfma_f32_16x16x32_f16

// ws layout (floats): [0,1024) p2[q]; [1024,1280) v2[t]; [1280,+327680) pfrag
#define WS_PF 1280

// ---------------------------------------------------------------------------
// Prep: 64 blocks x 256; block b owns N-tile b.  Coalesced float4 stage of 16
// contiguous pred rows -> LDS, coalesced pfrag writes, shuffle p2/v2.
// ---------------------------------------------------------------------------
__global__ __launch_bounds__(256) void prep_all(const float* __restrict__ preds,
                                                const float* __restrict__ tgt,
                                                float* __restrict__ ws)
{
    __shared__ __align__(16) float ext[16][308];
    const int b   = blockIdx.x;          // = nt
    const int tid = threadIdx.x;

    {
        const float4* src = (const float4*)(preds + b*16*KD);
        for (int i = tid; i < 1200; i += 256) {
            int row = i / 75;
            int c   = i - row*75;
            *(float4*)&ext[row][c*4] = src[i];
        }
    }
    __syncthreads();

    f16x8* pf = (f16x8*)(ws + WS_PF) + b*1280;
    for (int j = tid; j < 1280; j += 256) {
        int lane = j & 63;
        int r    = j >> 6;               // = ks*2 + s
        int s    = r & 1;
        int ks   = r >> 1;
        int qr   = lane & 15;
        int kb   = ks*32 + (lane >> 4)*8;
        f16x8 v;
        #pragma unroll
        for (int jj = 0; jj < 8; ++jj) {
            int k = kb + jj;
            float x = (k < KD) ? ext[qr][k] : 0.f;
            f16 h = (f16)x;
            v[jj] = s ? (f16)(x - (float)h) : h;
        }
        pf[j] = v;
    }

    const int wv   = tid >> 6;           // 0..3
    const int lane = tid & 63;
    #pragma unroll
    for (int rr = 0; rr < 4; ++rr) {
        int row = wv*4 + rr;
        float s = 0.f;
        for (int k = lane; k < KD; k += 64) s = fmaf(ext[row][k], ext[row][k], s);
        #pragma unroll
        for (int m = 1; m < 64; m <<= 1) s += __shfl_xor(s, m, 64);
        if (lane == 0) ws[b*16 + row] = s;
    }
    {
        const float* base = tgt + (b*4 + wv)*KD;
        float s = 0.f;
        for (int k = lane; k < KD; k += 64) s = fmaf(base[k], base[k], s);
        #pragma unroll
        for (int m = 1; m < 64; m <<= 1) s += __shfl_xor(s, m, 64);
        if (lane == 0) ws[1024 + b*4 + wv] = s;
    }
}

// ---------------------------------------------------------------------------
// One sweep: NMT M-tiles x 4 N-tiles, acc 64 regs (proven no-spill).
// B software-pipelined: bh prefetched one ks ahead; acc chain reordered
// (ah*bh, alo*bh, ah*bl) so bl -- loaded at iteration top -- is consumed
// last, covered by ~2/3 of the iteration's MFMA issue.
// ---------------------------------------------------------------------------
template<int MTB, int NMT>
__device__ __forceinline__ void sweep(const f16 (*sext)[8][EXTLEN],
                                      const f16x8* __restrict__ pfrag,
                                      int ntg0, int lane, int col, int rg, int cA,
                                      float v2t, const float (&p2v)[4],
                                      float (&minD)[4], int (&minI)[4],
                                      float (*sopen)[512], int ntl0)
{
    f32x4 acc[NMT][4];
    #pragma unroll
    for (int h = 0; h < NMT; ++h)
        #pragma unroll
        for (int nt = 0; nt < 4; ++nt) acc[h][nt] = (f32x4){0.f,0.f,0.f,0.f};

    f16x8 bhc[4];                              // prefetched bh for current ks
    #pragma unroll
    for (int nt = 0; nt < 4; ++nt)
        bhc[nt] = pfrag[((ntg0+nt)*KSTEPS)*128 + lane];

    #pragma clang loop unroll(disable)
    for (int ks = 0; ks < KSTEPS; ++ks) {
        const int kn = (ks+1 < KSTEPS) ? ks+1 : ks;
        f16x8 blc[4], bhn[4];
        #pragma unroll
        for (int nt = 0; nt < 4; ++nt) {
            const int fi = ((ntg0+nt)*KSTEPS + ks)*128 + lane;
            blc[nt] = pfrag[fi + 64];                              // bl (cur)
            bhn[nt] = pfrag[((ntg0+nt)*KSTEPS + kn)*128 + lane];   // bh (next)
        }
        f16x8 ah[NMT], alo[NMT];
        #pragma unroll
        for (int h = 0; h < NMT; ++h) {
            const int mt  = MTB + h;                   // compile-time
            const int mtp = (mt < 7) ? mt : mt-7;
            const int sel = (mt < 7) ? 0 : 2;
            const int idx = EXTOFF + 300 - 48*mtp - 3*col + 8*rg - cA + 32*ks;
            ah[h]  = *(const f16x8*)&sext[sel  ][cA][idx];
            alo[h] = *(const f16x8*)&sext[sel+1][cA][idx];
        }
        #pragma unroll
        for (int nt = 0; nt < 4; ++nt) {
            #pragma unroll
            for (int h = 0; h < NMT; ++h) {
                acc[h][nt] = MFMA16(ah[h],  bhc[nt], acc[h][nt], 0,0,0);
                acc[h][nt] = MFMA16(alo[h], bhc[nt], acc[h][nt], 0,0,0);
            }
        }
        #pragma unroll
        for (int nt = 0; nt < 4; ++nt) {
            #pragma unroll
            for (int h = 0; h < NMT; ++h)
                acc[h][nt] = MFMA16(ah[h], blc[nt], acc[h][nt], 0,0,0);
        }
        #pragma unroll
        for (int nt = 0; nt < 4; ++nt) bhc[nt] = bhn[nt];
    }

    #pragma unroll
    for (int h = 0; h < NMT; ++h) {
        const int mt   = MTB + h;
        const int mtp  = (mt < 7) ? mt : mt-7;
        const int voff = (mt < 7) ? 0 : 100;
        const int ab   = mtp*16 + rg*4;
        #pragma unroll
        for (int nt = 0; nt < 4; ++nt) {
            const float s2 = v2t + p2v[nt];
            #pragma unroll
            for (int r = 0; r < 4; ++r) {
                const int al = ab + r;
                if (al < 100) {
                    float d2 = fmaxf(fmaf(-2.f, acc[h][nt][r], s2), 0.f) * 0.01f;
                    int vlog = voff + al;
                    if (d2 < minD[nt]) { minD[nt] = d2; minI[nt] = vlog; }
                    if (al == 0) sopen[voff ? 1 : 0][(ntl0+nt)*16 + col] = d2;
                }
            }
        }
    }
}

// ---------------------------------------------------------------------------
// One block = one target t x 512 queries (blockIdx.y halves N).  8 waves x
// 4 N-tiles.  LDS: sext 43K + red 16K + sopen 4K = 63 KB -> 2 blocks/CU.
// ---------------------------------------------------------------------------
__global__ __launch_bounds__(512) void matcher_mfma(
    const float* __restrict__ ws,      // p2 / v2 / pfrag
    const float* __restrict__ tgt,     // [256][300]
    const float* __restrict__ plog,    // [1024][2]
    const float* __restrict__ ptyp,    // [1024][4]
    const float* __restrict__ clog,    // [1024][2]
    const int*   __restrict__ labels,  // [256]
    const int*   __restrict__ iscl,    // [256]
    const float* __restrict__ clw,     // [256]
    float* __restrict__ out)           // [2][1024][256] flat fp32
{
    __shared__ __align__(16) f16 sext[4][8][EXTLEN];  // {Fh,Fl,Rh,Rl} x 8 copies
    __shared__ float redD[2048];
    __shared__ int   redI[2048];
    __shared__ float sopen[2][512];

    const int t    = blockIdx.x;
    const int nb   = blockIdx.y;        // 0..1
    const int tid  = threadIdx.x;
    const int lane = tid & 63;
    const int w    = tid >> 6;
    const int col  = lane & 15;
    const int rg   = lane >> 4;
    const int ntl0 = w*4;
    const int ntg0 = nb*32 + ntl0;

    // Stage ext (fwd+rev, hi+lo split, 8 byte-rotated copies).
    const float* tg = tgt + t*KD;
    for (int x = tid; x < EXTLEN; x += 512) {
        int e = x - EXTOFF;
        float vF = 0.f, vR = 0.f;
        if (e >= 0 && e < 600) {
            int m = (e >= 300) ? e - 300 : e;
            vF = tg[m];
            int jj = m / 3, c3 = m - 3*jj;
            vR = tg[(NPTS-1-jj)*3 + c3];
        }
        f16 fh = (f16)vF, fl = (f16)(vF - (float)fh);
        f16 rh = (f16)vR, rl = (f16)(vR - (float)rh);
        #pragma unroll
        for (int c = 0; c < 8; ++c) {
            int y = x - c;
            if (y >= 0) {
                sext[0][c][y] = fh; sext[1][c][y] = fl;
                sext[2][c][y] = rh; sext[3][c][y] = rl;
            }
        }
    }

    const float v2t = ws[1024 + t];
    float p2v[4];
    #pragma unroll
    for (int nt = 0; nt < 4; ++nt) p2v[nt] = ws[(ntg0+nt)*16 + col];
    const f16x8* __restrict__ pfrag = (const f16x8*)(ws + WS_PF);
    const int cA = (EXTOFF + 300 - 3*col) & 7;   // rotation copy (lane-fixed)
    __syncthreads();

    float minD[4]; int minI[4];
    #pragma unroll
    for (int nt = 0; nt < 4; ++nt) { minD[nt] = 3.4028235e38f; minI[nt] = 0; }

    sweep< 0,4>(sext, pfrag, ntg0, lane, col, rg, cA, v2t, p2v, minD, minI, sopen, ntl0);
    sweep< 4,4>(sext, pfrag, ntg0, lane, col, rg, cA, v2t, p2v, minD, minI, sopen, ntl0);
    sweep< 8,4>(sext, pfrag, ntg0, lane, col, rg, cA, v2t, p2v, minD, minI, sopen, ntl0);
    sweep<12,2>(sext, pfrag, ntg0, lane, col, rg, cA, v2t, p2v, minD, minI, sopen, ntl0);

    #pragma unroll
    for (int nt = 0; nt < 4; ++nt) {
        redD[(ntl0+nt)*64 + lane] = minD[nt];
        redI[(ntl0+nt)*64 + lane] = minI[nt];
    }
    __syncthreads();

    // Epilogue: one thread per local query.
    {
        const int lq   = tid;
        const int tile = lq >> 4;
        const int cc   = lq & 15;
        const int base = tile*64 + cc;
        float bd = redD[base]; int bi = redI[base];
        #pragma unroll
        for (int g = 1; g < 4; ++g) {
            float d = redD[base + g*16]; int i = redI[base + g*16];
            if (d < bd || (d == bd && i < bi)) { bd = d; bi = i; }
        }
        const int q = nb*512 + lq;
        int mapped = (bi <= NPTS-1) ? bi : (2*NPTS-1 - bi);
        float od   = fminf(sopen[0][lq], sopen[1][lq]);
        int   isc  = iscl[t];
        float geom = isc ? bd : od;
        int   ido  = isc ? mapped : 0;
        geom *= clw[t];

        float t0 = ptyp[q*4+0], t1 = ptyp[q*4+1];
        float t2 = ptyp[q*4+2], t3 = ptyp[q*4+3];
        float mx = fmaxf(fmaxf(t0,t1), fmaxf(t2,t3));
        float e0 = expf(t0-mx), e1 = expf(t1-mx), e2 = expf(t2-mx), e3 = expf(t3-mx);
        float rs = 1.0f/(e0+e1+e2+e3);
        int lab  = labels[t];
        float el = (lab == 0) ? e0 : (lab == 1) ? e1 : (lab == 2) ? e2 : e3;
        float cost = -logf(el*rs + EPSV);
        float v0 = plog[q*2+0], v1 = plog[q*2+1];
        cost += -logf(1.0f/(1.0f + expf(v1-v0)) + EPSV);
        float c0 = clog[q*2+0], c1 = clog[q*2+1];
        float pc = isc ? (1.0f/(1.0f + expf(c0-c1))) : (1.0f/(1.0f + expf(c1-c0)));
        cost += -logf(pc + EPSV);

        float C = geom + cost;
        out[q*T_TOT + t]               = C;
        out[Q_TOT*T_TOT + q*T_TOT + t] = (float)ido;
    }
}

extern "C" void kernel_launch(void* const* d_in, const int* in_sizes, int n_in,
                              void* d_out, int out_size, void* d_ws, size_t ws_size,
                              hipStream_t stream)
{
    const float* preds  = (const float*)d_in[0];  // pred_curve_points (1,1024,100,3)
    const float* plog   = (const float*)d_in[1];  // pred_curve_logits (1,1024,2)
    const float* ptyp   = (const float*)d_in[2];  // pred_curve_type   (1,1024,4)
    const float* clog   = (const float*)d_in[3];  // closed_curve_logits (1,1024,2)
    const float* tgt    = (const float*)d_in[4];  // tgt_curve_points  (256,100,3)
    const int*   labels = (const int*)d_in[5];    // tgt_labels (256)
    const int*   iscl   = (const int*)d_in[6];    // tgt_is_closed (256)
    const float* clw    = (const float*)d_in[7];  // curve_length_weighting (256)
    float* out = (float*)d_out;
    float* ws  = (float*)d_ws;    // 1280 + 327680 floats = 1.32 MB

    prep_all    <<<dim3(64),       dim3(256), 0, stream>>>(preds, tgt, ws);
    matcher_mfma<<<dim3(T_TOT, 2), dim3(512), 0, stream>>>(
        ws, tgt, plog, ptyp, clog, labels, iscl, clw, out);
}

// Round 20
// 161.842 us; speedup vs baseline: 1.0719x; 1.0719x over previous
//
#include <hip/hip_runtime.h>
#include <hip/hip_fp16.h>

#define Q_TOT 1024
#define T_TOT 256
#define NPTS  100
#define KD    300
#define EPSV  1e-6f

#define KSTEPS 10            // 10 * 32 = 320 >= 300 (zero-padded K)
#define EXTOFF 40            // front zero-pad for padded rows
#define EXTLEN 672           // f16 units per rotated copy

typedef _Float16 f16;
typedef _Float16 f16x8 __attribute__((ext_vector_type(8)));
typedef float    f32x4 __attribute__((ext_vector_type(4)));
#define MFMA16 __builtin_amdgcn_mfma_f32_16x16x32_f16

// ws layout (floats): [0,1024) p2[q]; [1024,1280) v2[t]; [1280,+327680) pfrag
#define WS_PF 1280

// ---------------------------------------------------------------------------
// Prep: 64 blocks x 256; block b owns N-tile b.  Coalesced float4 stage of 16
// contiguous pred rows -> LDS, coalesced pfrag writes, shuffle p2/v2.
// (R18-verified numerics.)
// ---------------------------------------------------------------------------
__global__ __launch_bounds__(256) void prep_all(const float* __restrict__ preds,
                                                const float* __restrict__ tgt,
                                                float* __restrict__ ws)
{
    __shared__ __align__(16) float ext[16][308];
    const int b   = blockIdx.x;          // = nt
    const int tid = threadIdx.x;

    {
        const float4* src = (const float4*)(preds + b*16*KD);
        for (int i = tid; i < 1200; i += 256) {
            int row = i / 75;
            int c   = i - row*75;
            *(float4*)&ext[row][c*4] = src[i];
        }
    }
    __syncthreads();

    f16x8* pf = (f16x8*)(ws + WS_PF) + b*1280;
    for (int j = tid; j < 1280; j += 256) {
        int lane = j & 63;
        int r    = j >> 6;               // = ks*2 + s
        int s    = r & 1;
        int ks   = r >> 1;
        int qr   = lane & 15;
        int kb   = ks*32 + (lane >> 4)*8;
        f16x8 v;
        #pragma unroll
        for (int jj = 0; jj < 8; ++jj) {
            int k = kb + jj;
            float x = (k < KD) ? ext[qr][k] : 0.f;
            f16 h = (f16)x;
            v[jj] = s ? (f16)(x - (float)h) : h;
        }
        pf[j] = v;
    }

    const int wv   = tid >> 6;           // 0..3
    const int lane = tid & 63;
    #pragma unroll
    for (int rr = 0; rr < 4; ++rr) {
        int row = wv*4 + rr;
        float s = 0.f;
        for (int k = lane; k < KD; k += 64) s = fmaf(ext[row][k], ext[row][k], s);
        #pragma unroll
        for (int m = 1; m < 64; m <<= 1) s += __shfl_xor(s, m, 64);
        if (lane == 0) ws[b*16 + row] = s;
    }
    {
        const float* base = tgt + (b*4 + wv)*KD;
        float s = 0.f;
        for (int k = lane; k < KD; k += 64) s = fmaf(base[k], base[k], s);
        #pragma unroll
        for (int m = 1; m < 64; m <<= 1) s += __shfl_xor(s, m, 64);
        if (lane == 0) ws[1024 + b*4 + wv] = s;
    }
}

// ---------------------------------------------------------------------------
// One sweep: 7 M-tiles x 2 N-tiles (all-fwd or all-bwd -> sel/voff compile-
// time, mtp = h).  acc[7][2] = 56 regs.  A operands PHASED to cap pressure:
// load ah[7] -> ah*bh + ah*bl (ah dies) -> load alo[7] -> alo*bh.
// Peak ~ acc56 + A28 + B16 + state < 128 (the spill cliff).
// ---------------------------------------------------------------------------
template<int SEL, int VOFF>
__device__ __forceinline__ void sweep2(const f16 (*sext)[8][EXTLEN],
                                       const f16x8* __restrict__ pfrag,
                                       int ntg0, int lane, int col, int rg, int cA,
                                       float v2t, const float (&p2v)[2],
                                       float (&minD)[2], int (&minI)[2],
                                       float (*sopen)[256], int ntl0)
{
    f32x4 acc[7][2];
    #pragma unroll
    for (int h = 0; h < 7; ++h)
        #pragma unroll
        for (int nt = 0; nt < 2; ++nt) acc[h][nt] = (f32x4){0.f,0.f,0.f,0.f};

    #pragma clang loop unroll(disable)
    for (int ks = 0; ks < KSTEPS; ++ks) {
        f16x8 bh[2], bl[2];
        #pragma unroll
        for (int nt = 0; nt < 2; ++nt) {
            const int fi = ((ntg0+nt)*KSTEPS + ks)*128 + lane;
            bh[nt] = pfrag[fi];
            bl[nt] = pfrag[fi + 64];
        }
        {
            f16x8 ah[7];
            #pragma unroll
            for (int h = 0; h < 7; ++h) {
                const int idx = EXTOFF + 300 - 48*h - 3*col + 8*rg - cA + 32*ks;
                ah[h] = *(const f16x8*)&sext[SEL][cA][idx];
            }
            #pragma unroll
            for (int nt = 0; nt < 2; ++nt)
                #pragma unroll
                for (int h = 0; h < 7; ++h)
                    acc[h][nt] = MFMA16(ah[h], bh[nt], acc[h][nt], 0,0,0);
            #pragma unroll
            for (int nt = 0; nt < 2; ++nt)
                #pragma unroll
                for (int h = 0; h < 7; ++h)
                    acc[h][nt] = MFMA16(ah[h], bl[nt], acc[h][nt], 0,0,0);
        }
        {
            f16x8 alo[7];
            #pragma unroll
            for (int h = 0; h < 7; ++h) {
                const int idx = EXTOFF + 300 - 48*h - 3*col + 8*rg - cA + 32*ks;
                alo[h] = *(const f16x8*)&sext[SEL+1][cA][idx];
            }
            #pragma unroll
            for (int nt = 0; nt < 2; ++nt)
                #pragma unroll
                for (int h = 0; h < 7; ++h)
                    acc[h][nt] = MFMA16(alo[h], bh[nt], acc[h][nt], 0,0,0);
        }
    }

    #pragma unroll
    for (int h = 0; h < 7; ++h) {
        const int ab = h*16 + rg*4;
        #pragma unroll
        for (int nt = 0; nt < 2; ++nt) {
            const float s2 = v2t + p2v[nt];
            #pragma unroll
            for (int r = 0; r < 4; ++r) {
                const int al = ab + r;
                if (al < 100) {
                    float d2 = fmaxf(fmaf(-2.f, acc[h][nt][r], s2), 0.f) * 0.01f;
                    int vlog = VOFF + al;
                    if (d2 < minD[nt]) { minD[nt] = d2; minI[nt] = vlog; }
                    if (al == 0) sopen[VOFF ? 1 : 0][(ntl0+nt)*16 + col] = d2;
                }
            }
        }
    }
}

// ---------------------------------------------------------------------------
// One block = one target t x 256 queries (blockIdx.y quarters N).  8 waves x
// 2 N-tiles; 2 sweeps (fwd, bwd) -> B L2 traffic halved vs R17-19.
// LDS: sext 43K + red 8K + sopen 2K = 53 KB.
// ---------------------------------------------------------------------------
__global__ __launch_bounds__(512) void matcher_mfma(
    const float* __restrict__ ws,      // p2 / v2 / pfrag
    const float* __restrict__ tgt,     // [256][300]
    const float* __restrict__ plog,    // [1024][2]
    const float* __restrict__ ptyp,    // [1024][4]
    const float* __restrict__ clog,    // [1024][2]
    const int*   __restrict__ labels,  // [256]
    const int*   __restrict__ iscl,    // [256]
    const float* __restrict__ clw,     // [256]
    float* __restrict__ out)           // [2][1024][256] flat fp32
{
    __shared__ __align__(16) f16 sext[4][8][EXTLEN];  // {Fh,Fl,Rh,Rl} x 8 copies
    __shared__ float redD[1024];
    __shared__ int   redI[1024];
    __shared__ float sopen[2][256];

    const int t    = blockIdx.x;
    const int nb   = blockIdx.y;        // 0..3
    const int tid  = threadIdx.x;
    const int lane = tid & 63;
    const int w    = tid >> 6;
    const int col  = lane & 15;
    const int rg   = lane >> 4;
    const int ntl0 = w*2;               // local N-tile base (0..14)
    const int ntg0 = nb*16 + ntl0;      // global N-tile base

    // Stage ext (fwd+rev, hi+lo split, 8 byte-rotated copies).
    const float* tg = tgt + t*KD;
    for (int x = tid; x < EXTLEN; x += 512) {
        int e = x - EXTOFF;
        float vF = 0.f, vR = 0.f;
        if (e >= 0 && e < 600) {
            int m = (e >= 300) ? e - 300 : e;
            vF = tg[m];
            int jj = m / 3, c3 = m - 3*jj;
            vR = tg[(NPTS-1-jj)*3 + c3];
        }
        f16 fh = (f16)vF, fl = (f16)(vF - (float)fh);
        f16 rh = (f16)vR, rl = (f16)(vR - (float)rh);
        #pragma unroll
        for (int c = 0; c < 8; ++c) {
            int y = x - c;
            if (y >= 0) {
                sext[0][c][y] = fh; sext[1][c][y] = fl;
                sext[2][c][y] = rh; sext[3][c][y] = rl;
            }
        }
    }

    const float v2t = ws[1024 + t];
    float p2v[2];
    #pragma unroll
    for (int nt = 0; nt < 2; ++nt) p2v[nt] = ws[(ntg0+nt)*16 + col];
    const f16x8* __restrict__ pfrag = (const f16x8*)(ws + WS_PF);
    const int cA = (EXTOFF + 300 - 3*col) & 7;   // rotation copy (lane-fixed)
    __syncthreads();

    float minD[2]; int minI[2];
    #pragma unroll
    for (int nt = 0; nt < 2; ++nt) { minD[nt] = 3.4028235e38f; minI[nt] = 0; }

    sweep2<0,  0>(sext, pfrag, ntg0, lane, col, rg, cA, v2t, p2v, minD, minI, sopen, ntl0);
    sweep2<2,100>(sext, pfrag, ntg0, lane, col, rg, cA, v2t, p2v, minD, minI, sopen, ntl0);

    #pragma unroll
    for (int nt = 0; nt < 2; ++nt) {
        redD[(ntl0+nt)*64 + lane] = minD[nt];
        redI[(ntl0+nt)*64 + lane] = minI[nt];
    }
    __syncthreads();

    // Epilogue: threads 0..255, one local query each.
    if (tid < 256) {
        const int lq   = tid;
        const int tile = lq >> 4;
        const int cc   = lq & 15;
        const int base = tile*64 + cc;
        float bd = redD[base]; int bi = redI[base];
        #pragma unroll
        for (int g = 1; g < 4; ++g) {
            float d = redD[base + g*16]; int i = redI[base + g*16];
            if (d < bd || (d == bd && i < bi)) { bd = d; bi = i; }
        }
        const int q = nb*256 + lq;
        int mapped = (bi <= NPTS-1) ? bi : (2*NPTS-1 - bi);
        float od   = fminf(sopen[0][lq], sopen[1][lq]);
        int   isc  = iscl[t];
        float geom = isc ? bd : od;
        int   ido  = isc ? mapped : 0;
        geom *= clw[t];

        float t0 = ptyp[q*4+0], t1 = ptyp[q*4+1];
        float t2 = ptyp[q*4+2], t3 = ptyp[q*4+3];
        float mx = fmaxf(fmaxf(t0,t1), fmaxf(t2,t3));
        float e0 = expf(t0-mx), e1 = expf(t1-mx), e2 = expf(t2-mx), e3 = expf(t3-mx);
        float rs = 1.0f/(e0+e1+e2+e3);
        int lab  = labels[t];
        float el = (lab == 0) ? e0 : (lab == 1) ? e1 : (lab == 2) ? e2 : e3;
        float cost = -logf(el*rs + EPSV);
        float v0 = plog[q*2+0], v1 = plog[q*2+1];
        cost += -logf(1.0f/(1.0f + expf(v1-v0)) + EPSV);
        float c0 = clog[q*2+0], c1 = clog[q*2+1];
        float pc = isc ? (1.0f/(1.0f + expf(c0-c1))) : (1.0f/(1.0f + expf(c1-c0)));
        cost += -logf(pc + EPSV);

        float C = geom + cost;
        out[q*T_TOT + t]               = C;
        out[Q_TOT*T_TOT + q*T_TOT + t] = (float)ido;
    }
}

extern "C" void kernel_launch(void* const* d_in, const int* in_sizes, int n_in,
                              void* d_out, int out_size, void* d_ws, size_t ws_size,
                              hipStream_t stream)
{
    const float* preds  = (const float*)d_in[0];  // pred_curve_points (1,1024,100,3)
    const float* plog   = (const float*)d_in[1];  // pred_curve_logits (1,1024,2)
    const float* ptyp   = (const float*)d_in[2];  // pred_curve_type   (1,1024,4)
    const float* clog   = (const float*)d_in[3];  // closed_curve_logits (1,1024,2)
    const float* tgt    = (const float*)d_in[4];  // tgt_curve_points  (256,100,3)
    const int*   labels = (const int*)d_in[5];    // tgt_labels (256)
    const int*   iscl   = (const int*)d_in[6];    // tgt_is_closed (256)
    const float* clw    = (const float*)d_in[7];  // curve_length_weighting (256)
    float* out = (float*)d_out;
    float* ws  = (float*)d_ws;    // 1280 + 327680 floats = 1.32 MB

    prep_all    <<<dim3(64),       dim3(256), 0, stream>>>(preds, tgt, ws);
    matcher_mfma<<<dim3(T_TOT, 4), dim3(512), 0, stream>>>(
        ws, tgt, plog, ptyp, clog, labels, iscl, clw, out);
}